// Round 5
// baseline (299.419 us; speedup 1.0000x reference)
//
#include <hip/hip_runtime.h>
#include <math.h>

#define B_ 2
#define T_ 2048
#define C_ 1024
#define H_ 16
#define D_ 64
#define M_ (B_*T_)

typedef unsigned short u16;
typedef unsigned int u32;
typedef __attribute__((ext_vector_type(8))) short short8;
typedef __attribute__((ext_vector_type(4))) float f32x4;

__device__ inline u16 f2bf(float f){
  union { float f; unsigned u; } v; v.f = f;
  unsigned r = (v.u + 0x7FFF + ((v.u >> 16) & 1)) >> 16;
  return (u16)r;
}

__device__ inline void gload_lds16(const void* g, void* l){
  __builtin_amdgcn_global_load_lds(
      (const __attribute__((address_space(1))) unsigned*)g,
      (__attribute__((address_space(3))) unsigned*)l, 16, 0, 0);
}

// byte offset into a [rows][64]u16 (128B-row) LDS tile with 16B-chunk XOR swizzle
__device__ inline int swzb(int row, int chunk){
  return (row << 7) | ((chunk ^ (row & 7)) << 4);
}

// ---------------- x -> bf16 ----------------
__global__ void k_cvt_x(const float* __restrict__ x, u16* __restrict__ xb){
  int i = (blockIdx.x * 256 + threadIdx.x) * 8;
  float4 a = *(const float4*)(x + i);
  float4 b = *(const float4*)(x + i + 4);
  short8 o;
  o[0] = (short)f2bf(a.x); o[1] = (short)f2bf(a.y);
  o[2] = (short)f2bf(a.z); o[3] = (short)f2bf(a.w);
  o[4] = (short)f2bf(b.x); o[5] = (short)f2bf(b.y);
  o[6] = (short)f2bf(b.z); o[7] = (short)f2bf(b.w);
  *(short8*)(xb + i) = o;
}

// ---------------- W [K][N] fp32 -> Wt [N][K] bf16 ----------------
__global__ void k_transW(const float* __restrict__ W, u16* __restrict__ Wt, int K, int N){
  __shared__ float t[32][33];
  int bn = blockIdx.x * 32, bk = blockIdx.y * 32;
  int tx = threadIdx.x, ty = threadIdx.y; // (32,8)
  #pragma unroll
  for (int i = 0; i < 32; i += 8)
    t[ty + i][tx] = W[(size_t)(bk + ty + i) * N + bn + tx];
  __syncthreads();
  #pragma unroll
  for (int i = 0; i < 32; i += 8)
    Wt[(size_t)(bn + ty + i) * K + bk + tx] = f2bf(t[tx][ty + i]);
}

// ---------------- v [bh][T][D] -> vt [bh][D][T] (bf16) ----------------
__global__ void k_transV(const u16* __restrict__ v, u16* __restrict__ vt){
  __shared__ u16 t[32][33];
  int bh = blockIdx.z;
  int t0 = blockIdx.x * 32, d0 = blockIdx.y * 32;
  int tx = threadIdx.x, ty = threadIdx.y;
  const u16* vs = v + (size_t)bh * T_ * D_;
  u16* vd = vt + (size_t)bh * T_ * D_;
  #pragma unroll
  for (int i = 0; i < 32; i += 8)
    t[ty + i][tx] = vs[(size_t)(t0 + ty + i) * D_ + d0 + tx];
  __syncthreads();
  #pragma unroll
  for (int i = 0; i < 32; i += 8)
    vd[(size_t)(d0 + ty + i) * T_ + t0 + tx] = t[tx][ty + i];
}

// ---------------- 128x128 GEMM, A[M][K] * Bt[N][K]^T, bf16 MFMA ----------------
// XCD-chunked block swizzle (T1): requires gridDim.x*gridDim.y % 8 == 0.
template<int EPI>
__launch_bounds__(256, 2)
__global__ void k_gemm(const u16* __restrict__ A, const u16* __restrict__ Bt,
                       const float* __restrict__ bias, float* __restrict__ outF,
                       u16* __restrict__ oq, u16* __restrict__ ok, u16* __restrict__ ov,
                       int M, int N, int K){
  __shared__ u16 lA[128 * 32];
  __shared__ u16 lB[128 * 32];
  int tid = threadIdx.x, lane = tid & 63, wv = tid >> 6;
  unsigned nwg = gridDim.x * gridDim.y;
  unsigned bid = blockIdx.y * gridDim.x + blockIdx.x;
  unsigned nbid = (bid & 7) * (nwg >> 3) + (bid >> 3);
  int bm = (int)(nbid / gridDim.x) * 128, bn = (int)(nbid % gridDim.x) * 128;
  int wr = (wv >> 1) * 64, wc = (wv & 1) * 64;
  f32x4 acc[4][4] = {};

  const u16* Ab = A + (size_t)(bm + wv * 32 + (lane >> 2)) * K + (lane & 3) * 8;
  const u16* Bb = Bt + (size_t)(bn + wv * 32 + (lane >> 2)) * K + (lane & 3) * 8;
  u16* lAd = &lA[wv * 1024];
  u16* lBd = &lB[wv * 1024];
  int ar = wr + (lane & 15);
  int br = wc + (lane & 15);
  int kc = (lane >> 4) * 8;

  for (int k0 = 0; k0 < K; k0 += 32){
    gload_lds16(Ab + k0, lAd);
    gload_lds16(Ab + k0 + (size_t)16 * K, lAd + 512);
    gload_lds16(Bb + k0, lBd);
    gload_lds16(Bb + k0 + (size_t)16 * K, lBd + 512);
    __syncthreads();
    short8 afr[4], bfr[4];
    #pragma unroll
    for (int m = 0; m < 4; m++) afr[m] = *(const short8*)&lA[(ar + m * 16) * 32 + kc];
    #pragma unroll
    for (int n = 0; n < 4; n++) bfr[n] = *(const short8*)&lB[(br + n * 16) * 32 + kc];
    #pragma unroll
    for (int m = 0; m < 4; m++)
      #pragma unroll
      for (int n = 0; n < 4; n++)
        acc[m][n] = __builtin_amdgcn_mfma_f32_16x16x32_bf16(afr[m], bfr[n], acc[m][n], 0, 0, 0);
    __syncthreads();
  }

  if (EPI == 1){
    #pragma unroll
    for (int m = 0; m < 4; m++){
      int gmB = bm + wr + m * 16 + ((lane >> 4) << 2);
      #pragma unroll
      for (int n = 0; n < 4; n++){
        int gn = bn + wc + n * 16 + (lane & 15);
        float bia = bias[gn];
        #pragma unroll
        for (int j = 0; j < 4; j++)
          outF[(size_t)(gmB + j) * N + gn] = acc[m][n][j] + bia;
      }
    }
  } else {
    #pragma unroll
    for (int m = 0; m < 4; m++){
      int gmB = bm + wr + m * 16 + ((lane >> 4) << 2);
      #pragma unroll
      for (int n = 0; n < 4; n++){
        int gn = bn + wc + n * 16 + (lane & 15);
        float bia = bias[gn];
        int part = gn >> 10;
        int col = gn & 1023;
        int h = col >> 6, d = col & 63;
        u16* dst = (part == 0) ? oq : (part == 1) ? ok : ov;
        #pragma unroll
        for (int j = 0; j < 4; j++){
          int gm = gmB + j;
          int b = gm >> 11, t = gm & 2047;
          dst[((size_t)(b * H_ + h) * T_ + t) * D_ + d] = f2bf(acc[m][n][j] + bia);
        }
      }
    }
  }
}

// ---------------- flash attention: split-KV, 4 waves / 32 q-rows ----------------
// q,k: [bh][T][D] bf16; vt: [bh][D][T] bf16; y: [b][t][C] bf16 (head-major cols)
// S^T = mfma(K,Q): lane holds q=lane&15, kv = n*16 + 4*(lane>>4) + r
// O^T = mfma(V^T,P^T): lane holds q=lane&15, d = n*16 + 4*(lane>>4) + r
// Wave w processes kv-tiles t = ntiles-1-w, ntiles-5-w, ... (descending:
// diagonal-first maximizes defer-max skips). No barriers in the main loop;
// single end merge: m* = max_w m_w, O* = sum_w O_w*2^(m_w-m*), same for l.
__launch_bounds__(256, 3)
__global__ void k_attn(const u16* __restrict__ q, const u16* __restrict__ k,
                       const u16* __restrict__ vt, u16* __restrict__ y,
                       const float* __restrict__ tempPtr){
  __shared__ u16 lP[4][2048];          // per-wave [q][kv], XOR-swizzled
  __shared__ float obuf[32][66];       // merge: O accum, pad 66 (conflict-free)
  __shared__ float mbuf[4][2][16];     // per-wave running max
  __shared__ float lsbuf[2][16];       // merged denominator
  const float LOG2E = 1.44269504089f;
  int tid = threadIdx.x, lane = tid & 63, wv = tid >> 6;
  int g = lane >> 4, c = lane & 15;
  int bh = blockIdx.x, h = bh & (H_ - 1), b = bh >> 4;
  int qt = 63 - blockIdx.y;            // longest q-tiles dispatched first
  int qb = qt * 32;

  // zero merge buffers (visible after the merge barrier)
  for (int i = tid; i < 32 * 66; i += 256) ((float*)obuf)[i] = 0.f;
  if (tid < 32) ((float*)lsbuf)[tid] = 0.f;

  float scl2 = LOG2E / (8.0f * tempPtr[0]);
  float slope2 = exp2f(-0.5f * (float)(h + 1)) * LOG2E;
  const u16* qp = q + (size_t)bh * T_ * D_;
  const u16* kp = k + (size_t)bh * T_ * D_;
  const u16* vp = vt + (size_t)bh * T_ * D_;
  char* lPw = (char*)lP[wv];

  // Q fragments (B-operand of S^T): lane holds Q[qb+m*16+c][ks*32+g*8 ..+7]
  short8 qf[2][2];
  #pragma unroll
  for (int m = 0; m < 2; m++)
    #pragma unroll
    for (int ks = 0; ks < 2; ks++)
      qf[m][ks] = *(const short8*)&qp[(size_t)(qb + m * 16 + c) * D_ + ks * 32 + g * 8];

  float dq0 = (float)(g * 4 - c - qb); // s = accs*scl2 + slope2*((kv0+n*16+r) + dq0 - 16m)
  float mrun[2] = { -1e30f, -1e30f }, lrun[2] = { 0.f, 0.f };
  f32x4 acco[2][4] = {};

  int ntiles = (qb + 95) >> 6;
  for (int t = ntiles - 1 - wv; t >= 0; t -= 4){
    int kv0 = t << 6;

    // ---- S^T = K * Q^T (K frags straight from global) ----
    f32x4 accs[2][4] = {};
    #pragma unroll
    for (int ks = 0; ks < 2; ks++){
      short8 kf[4];
      #pragma unroll
      for (int n = 0; n < 4; n++)
        kf[n] = *(const short8*)&kp[(size_t)(kv0 + n * 16 + c) * D_ + ks * 32 + g * 8];
      #pragma unroll
      for (int m = 0; m < 2; m++)
        #pragma unroll
        for (int n = 0; n < 4; n++)
          accs[m][n] = __builtin_amdgcn_mfma_f32_16x16x32_bf16(kf[n], qf[m][ks], accs[m][n], 0, 0, 0);
    }

    // ---- V frags issued EARLY (consumed after softmax: latency hidden) ----
    short8 vf[2][4];
    #pragma unroll
    for (int ks = 0; ks < 2; ks++)
      #pragma unroll
      for (int n = 0; n < 4; n++)
        vf[ks][n] = *(const short8*)&vp[(size_t)(n * 16 + c) * T_ + kv0 + ks * 32 + g * 8];

    bool maskt = (kv0 + 64 > qb);      // only the diagonal tile needs masking
    #pragma unroll
    for (int m = 0; m < 2; m++){
      float tv = (float)kv0 + dq0 - (float)(16 * m);
      float s[16];
      #pragma unroll
      for (int n = 0; n < 4; n++)
        #pragma unroll
        for (int r = 0; r < 4; r++)
          s[n * 4 + r] = fmaf(slope2, tv + (float)(n * 16 + r), accs[m][n][r] * scl2);
      if (maskt){
        int qm = qb + m * 16 + c - kv0;
        int kvg = g * 4;
        #pragma unroll
        for (int n = 0; n < 4; n++)
          #pragma unroll
          for (int r = 0; r < 4; r++)
            s[n * 4 + r] = (n * 16 + kvg + r > qm) ? -1e30f : s[n * 4 + r];
      }
      float pm = s[0];
      #pragma unroll
      for (int i = 1; i < 16; i++) pm = fmaxf(pm, s[i]);
      pm = fmaxf(pm, __shfl_xor(pm, 16));
      pm = fmaxf(pm, __shfl_xor(pm, 32));
      if (!__all(pm <= mrun[m] + 8.0f)){   // defer-max: skip rescale on small growth
        float nm = fmaxf(mrun[m], pm);
        float al = exp2f(mrun[m] - nm);
        lrun[m] *= al;
        #pragma unroll
        for (int n = 0; n < 4; n++)
          #pragma unroll
          for (int r = 0; r < 4; r++)
            acco[m][n][r] *= al;
        mrun[m] = nm;
      }
      float p[16], ps = 0.f;
      #pragma unroll
      for (int i = 0; i < 16; i++){ p[i] = exp2f(s[i] - mrun[m]); ps += p[i]; }
      lrun[m] += ps;                       // per-lane partial; merged at the end
      #pragma unroll
      for (int n = 0; n < 4; n++){
        u32 w0 = ((u32)f2bf(p[n * 4 + 1]) << 16) | f2bf(p[n * 4 + 0]);
        u32 w1 = ((u32)f2bf(p[n * 4 + 3]) << 16) | f2bf(p[n * 4 + 2]);
        uint2 wp; wp.x = w0; wp.y = w1;
        *(uint2*)(lPw + swzb(c + 16 * m, 2 * n + (g >> 1)) + ((g & 1) << 3)) = wp;
      }
    }

    // ---- O^T += V^T * P^T (P from private LDS) ----
    #pragma unroll
    for (int ks = 0; ks < 2; ks++){
      short8 pf[2];
      #pragma unroll
      for (int m = 0; m < 2; m++)
        pf[m] = *(const short8*)(lPw + swzb(c + 16 * m, ks * 4 + g));
      #pragma unroll
      for (int m = 0; m < 2; m++)
        #pragma unroll
        for (int n = 0; n < 4; n++)
          acco[m][n] = __builtin_amdgcn_mfma_f32_16x16x32_bf16(vf[ks][n], pf[m], acco[m][n], 0, 0, 0);
    }
  }

  // ---- cross-wave merge ----
  float ls[2];
  #pragma unroll
  for (int m = 0; m < 2; m++){
    float v = lrun[m];
    v += __shfl_xor(v, 16);
    v += __shfl_xor(v, 32);
    ls[m] = v;                           // full row sum (uniform across g)
  }
  if (lane < 16){ mbuf[wv][0][c] = mrun[0]; mbuf[wv][1][c] = mrun[1]; }
  __syncthreads();
  #pragma unroll
  for (int m = 0; m < 2; m++){
    float mstar = fmaxf(fmaxf(mbuf[0][m][c], mbuf[1][m][c]),
                        fmaxf(mbuf[2][m][c], mbuf[3][m][c]));
    float f = exp2f(mrun[m] - mstar);    // 0 for idle/empty waves
    if (lane < 16) atomicAdd(&lsbuf[m][c], ls[m] * f);
    #pragma unroll
    for (int n = 0; n < 4; n++)
      #pragma unroll
      for (int r = 0; r < 4; r++)
        atomicAdd(&obuf[m * 16 + c][n * 16 + g * 4 + r], acco[m][n][r] * f);
  }
  __syncthreads();

  // ---- write out: thread -> (row = tid>>3, 8 d-cols) ----
  {
    int row = tid >> 3, d0 = (tid & 7) * 8;
    float linv = 1.0f / lsbuf[row >> 4][row & 15];
    u32 wp[4];
    #pragma unroll
    for (int jj = 0; jj < 4; jj++){
      u16 lo = f2bf(obuf[row][d0 + 2 * jj] * linv);
      u16 hi = f2bf(obuf[row][d0 + 2 * jj + 1] * linv);
      wp[jj] = ((u32)hi << 16) | lo;
    }
    uint4 o4; o4.x = wp[0]; o4.y = wp[1]; o4.z = wp[2]; o4.w = wp[3];
    *(uint4*)&y[(size_t)(b * T_ + qb + row) * C_ + h * D_ + d0] = o4;
  }
}

// ---------------- launcher ----------------
// Workspace layout (40 MB peak, aliased by lifetime):
//   [0,  8)  xb  -> vtw   [8,14) wab   [14,16) wpt
//   [16,24) qw   [24,32) kw   [32,40) vw -> yb
extern "C" void kernel_launch(void* const* d_in, const int* in_sizes, int n_in,
                              void* d_out, int out_size, void* d_ws, size_t ws_size,
                              hipStream_t stream){
  const float* x      = (const float*)d_in[0];
  const float* W_attn = (const float*)d_in[1];
  const float* b_attn = (const float*)d_in[2];
  const float* W_proj = (const float*)d_in[3];
  const float* b_proj = (const float*)d_in[4];
  const float* temp   = (const float*)d_in[5];
  float* out = (float*)d_out;

  if (ws_size < (size_t)41943040) return;  // need 40 MB scratch
  char* ws = (char*)d_ws;
  u16* xb  = (u16*)(ws);
  u16* wab = (u16*)(ws + 8388608);
  u16* wpt = (u16*)(ws + 14680064);
  u16* qw  = (u16*)(ws + 16777216);
  u16* kw  = (u16*)(ws + 25165824);
  u16* vw  = (u16*)(ws + 33554432);
  u16* vtw = (u16*)(ws);                    // overlays xb
  u16* yb  = (u16*)(ws + 33554432);         // overlays vw

  k_cvt_x<<<2048, 256, 0, stream>>>(x, xb);
  k_transW<<<dim3(96, 32), dim3(32, 8), 0, stream>>>(W_attn, wab, 1024, 3072);
  k_transW<<<dim3(32, 32), dim3(32, 8), 0, stream>>>(W_proj, wpt, 1024, 1024);
  k_gemm<0><<<dim3(24, 32), 256, 0, stream>>>(xb, wab, b_attn, nullptr, qw, kw, vw,
                                              4096, 3072, 1024);
  k_transV<<<dim3(64, 2, 32), dim3(32, 8), 0, stream>>>(vw, vtw);
  k_attn<<<dim3(32, 64), 256, 0, stream>>>(qw, kw, vtw, yb, temp);
  k_gemm<1><<<dim3(8, 32), 256, 0, stream>>>(yb, wpt, b_proj, out, nullptr, nullptr, nullptr,
                                             4096, 1024, 1024);
}

// Round 6
// 200.974 us; speedup vs baseline: 1.4898x; 1.4898x over previous
//
#include <hip/hip_runtime.h>
#include <math.h>

#define B_ 2
#define T_ 2048
#define C_ 1024
#define H_ 16
#define D_ 64
#define M_ (B_*T_)

typedef unsigned short u16;
typedef unsigned int u32;
typedef __attribute__((ext_vector_type(8))) short short8;
typedef __attribute__((ext_vector_type(4))) float f32x4;

__device__ inline u16 f2bf(float f){
  union { float f; unsigned u; } v; v.f = f;
  unsigned r = (v.u + 0x7FFF + ((v.u >> 16) & 1)) >> 16;
  return (u16)r;
}

__device__ inline void gload_lds16(const void* g, void* l){
  __builtin_amdgcn_global_load_lds(
      (const __attribute__((address_space(1))) unsigned*)g,
      (__attribute__((address_space(3))) unsigned*)l, 16, 0, 0);
}

// byte offset into a [rows][64]u16 (128B-row) LDS tile with 16B-chunk XOR swizzle
__device__ inline int swzb(int row, int chunk){
  return (row << 7) | ((chunk ^ (row & 7)) << 4);
}

// ---------------- x -> bf16 ----------------
__global__ void k_cvt_x(const float* __restrict__ x, u16* __restrict__ xb){
  int i = (blockIdx.x * 256 + threadIdx.x) * 8;
  float4 a = *(const float4*)(x + i);
  float4 b = *(const float4*)(x + i + 4);
  short8 o;
  o[0] = (short)f2bf(a.x); o[1] = (short)f2bf(a.y);
  o[2] = (short)f2bf(a.z); o[3] = (short)f2bf(a.w);
  o[4] = (short)f2bf(b.x); o[5] = (short)f2bf(b.y);
  o[6] = (short)f2bf(b.z); o[7] = (short)f2bf(b.w);
  *(short8*)(xb + i) = o;
}

// ---------------- W [K][N] fp32 -> Wt [N][K] bf16 ----------------
__global__ void k_transW(const float* __restrict__ W, u16* __restrict__ Wt, int K, int N){
  __shared__ float t[32][33];
  int bn = blockIdx.x * 32, bk = blockIdx.y * 32;
  int tx = threadIdx.x, ty = threadIdx.y; // (32,8)
  #pragma unroll
  for (int i = 0; i < 32; i += 8)
    t[ty + i][tx] = W[(size_t)(bk + ty + i) * N + bn + tx];
  __syncthreads();
  #pragma unroll
  for (int i = 0; i < 32; i += 8)
    Wt[(size_t)(bn + ty + i) * K + bk + tx] = f2bf(t[tx][ty + i]);
}

// ---------------- v [bh][T][D] -> vt [bh][D][T] (bf16) ----------------
__global__ void k_transV(const u16* __restrict__ v, u16* __restrict__ vt){
  __shared__ u16 t[32][33];
  int bh = blockIdx.z;
  int t0 = blockIdx.x * 32, d0 = blockIdx.y * 32;
  int tx = threadIdx.x, ty = threadIdx.y;
  const u16* vs = v + (size_t)bh * T_ * D_;
  u16* vd = vt + (size_t)bh * T_ * D_;
  #pragma unroll
  for (int i = 0; i < 32; i += 8)
    t[ty + i][tx] = vs[(size_t)(t0 + ty + i) * D_ + d0 + tx];
  __syncthreads();
  #pragma unroll
  for (int i = 0; i < 32; i += 8)
    vd[(size_t)(d0 + ty + i) * T_ + t0 + tx] = t[tx][ty + i];
}

// ---------------- 128x128 GEMM, A[M][K] * Bt[N][K]^T, bf16 MFMA ----------------
// XCD-chunked block swizzle (T1): requires gridDim.x*gridDim.y % 8 == 0.
template<int EPI>
__launch_bounds__(256, 2)
__global__ void k_gemm(const u16* __restrict__ A, const u16* __restrict__ Bt,
                       const float* __restrict__ bias, float* __restrict__ outF,
                       u16* __restrict__ oq, u16* __restrict__ ok, u16* __restrict__ ov,
                       int M, int N, int K){
  __shared__ u16 lA[128 * 32];
  __shared__ u16 lB[128 * 32];
  int tid = threadIdx.x, lane = tid & 63, wv = tid >> 6;
  unsigned nwg = gridDim.x * gridDim.y;
  unsigned bid = blockIdx.y * gridDim.x + blockIdx.x;
  unsigned nbid = (bid & 7) * (nwg >> 3) + (bid >> 3);
  int bm = (int)(nbid / gridDim.x) * 128, bn = (int)(nbid % gridDim.x) * 128;
  int wr = (wv >> 1) * 64, wc = (wv & 1) * 64;
  f32x4 acc[4][4] = {};

  const u16* Ab = A + (size_t)(bm + wv * 32 + (lane >> 2)) * K + (lane & 3) * 8;
  const u16* Bb = Bt + (size_t)(bn + wv * 32 + (lane >> 2)) * K + (lane & 3) * 8;
  u16* lAd = &lA[wv * 1024];
  u16* lBd = &lB[wv * 1024];
  int ar = wr + (lane & 15);
  int br = wc + (lane & 15);
  int kc = (lane >> 4) * 8;

  for (int k0 = 0; k0 < K; k0 += 32){
    gload_lds16(Ab + k0, lAd);
    gload_lds16(Ab + k0 + (size_t)16 * K, lAd + 512);
    gload_lds16(Bb + k0, lBd);
    gload_lds16(Bb + k0 + (size_t)16 * K, lBd + 512);
    __syncthreads();
    short8 afr[4], bfr[4];
    #pragma unroll
    for (int m = 0; m < 4; m++) afr[m] = *(const short8*)&lA[(ar + m * 16) * 32 + kc];
    #pragma unroll
    for (int n = 0; n < 4; n++) bfr[n] = *(const short8*)&lB[(br + n * 16) * 32 + kc];
    #pragma unroll
    for (int m = 0; m < 4; m++)
      #pragma unroll
      for (int n = 0; n < 4; n++)
        acc[m][n] = __builtin_amdgcn_mfma_f32_16x16x32_bf16(afr[m], bfr[n], acc[m][n], 0, 0, 0);
    __syncthreads();
  }

  if (EPI == 1){
    #pragma unroll
    for (int m = 0; m < 4; m++){
      int gmB = bm + wr + m * 16 + ((lane >> 4) << 2);
      #pragma unroll
      for (int n = 0; n < 4; n++){
        int gn = bn + wc + n * 16 + (lane & 15);
        float bia = bias[gn];
        #pragma unroll
        for (int j = 0; j < 4; j++)
          outF[(size_t)(gmB + j) * N + gn] = acc[m][n][j] + bia;
      }
    }
  } else {
    #pragma unroll
    for (int m = 0; m < 4; m++){
      int gmB = bm + wr + m * 16 + ((lane >> 4) << 2);
      #pragma unroll
      for (int n = 0; n < 4; n++){
        int gn = bn + wc + n * 16 + (lane & 15);
        float bia = bias[gn];
        int part = gn >> 10;
        int col = gn & 1023;
        int h = col >> 6, d = col & 63;
        u16* dst = (part == 0) ? oq : (part == 1) ? ok : ov;
        #pragma unroll
        for (int j = 0; j < 4; j++){
          int gm = gmB + j;
          int b = gm >> 11, t = gm & 2047;
          dst[((size_t)(b * H_ + h) * T_ + t) * D_ + d] = f2bf(acc[m][n][j] + bia);
        }
      }
    }
  }
}

// ---------------- flash attention: 4 waves x 16 q-rows, LDS dbuf K/V ----------------
// q,k: [bh][T][D] bf16; vt: [bh][D][T] bf16; y: [b][t][C] bf16 (head-major cols)
// S^T = mfma(K,Q): lane holds q=lane&15(=c), kv = n*16 + 4*(lane>>4) + r
// O^T = mfma(V^T,P^T): lane holds q=c, d = n*16 + 4*(lane>>4) + r
// ALiBi row-constant term (-slope*q) dropped: softmax is shift-invariant per
// row, so bias == slope*kv.  kv-tiles processed DESCENDING (diagonal first):
// running max is set on tile 1, defer-max skips every later rescale.
// K/V double-buffered in LDS (one barrier per tile); global loads have a
// 2-tile (~1200 cy) prefetch distance.
__launch_bounds__(256, 3)
__global__ void k_attn(const u16* __restrict__ q, const u16* __restrict__ k,
                       const u16* __restrict__ vt, u16* __restrict__ y,
                       const float* __restrict__ tempPtr){
  __shared__ u16 lK[2][64 * 64];       // [kv][d], XOR-swizzled
  __shared__ u16 lV[2][64 * 64];       // [d][kv], XOR-swizzled
  __shared__ u16 lP[4][16 * 64];       // per-wave [q][kv], XOR-swizzled
  const float LOG2E = 1.44269504089f;
  int tid = threadIdx.x, lane = tid & 63, wv = tid >> 6;
  int g = lane >> 4, c = lane & 15;
  int bh = blockIdx.x, h = bh & (H_ - 1), b = bh >> 4;
  int qt = 31 - blockIdx.y;            // longest q-tiles dispatched first
  int q0 = qt * 64;
  int qb = q0 + wv * 16;
  float scl2 = LOG2E / (8.0f * tempPtr[0]);
  float slope2 = exp2f(-0.5f * (float)(h + 1)) * LOG2E;
  const u16* qp = q + (size_t)bh * T_ * D_;
  const u16* kp = k + (size_t)bh * T_ * D_;
  const u16* vp = vt + (size_t)bh * T_ * D_;
  char* lPw = (char*)lP[wv];

  // Q fragments (B-operand of S^T): lane holds Q[qb+c][ks*32+g*8 ..+7]
  short8 qf[2];
  #pragma unroll
  for (int ks = 0; ks < 2; ks++)
    qf[ks] = *(const short8*)&qp[(size_t)(qb + c) * D_ + ks * 32 + g * 8];

  // per-lane ALiBi: bias = slope2*kv = slope2*kv0 + boff[i]
  float boff[16];
  #pragma unroll
  for (int n = 0; n < 4; n++)
    #pragma unroll
    for (int r = 0; r < 4; r++)
      boff[n * 4 + r] = slope2 * (float)(n * 16 + g * 4 + r);

  float mrun = -1e30f, lrun = 0.f;
  f32x4 acco[4] = {};

  // staging: thread covers row sr, 16B-chunks sc*2 / sc*2+1 of K and V tiles
  int sr = tid >> 2, sc = tid & 3;
  short8 rk0, rk1, rv0, rv1;

  // prologue: load+write tile qt, load tile qt-1
  {
    const u16* gk = kp + (size_t)(q0 + sr) * D_ + sc * 16;
    const u16* gv = vp + (size_t)sr * T_ + q0 + sc * 16;
    rk0 = *(const short8*)gk;       rk1 = *(const short8*)(gk + 8);
    rv0 = *(const short8*)gv;       rv1 = *(const short8*)(gv + 8);
    char* dK = (char*)lK[qt & 1];
    char* dV = (char*)lV[qt & 1];
    *(short8*)(dK + swzb(sr, sc * 2))     = rk0;
    *(short8*)(dK + swzb(sr, sc * 2 + 1)) = rk1;
    *(short8*)(dV + swzb(sr, sc * 2))     = rv0;
    *(short8*)(dV + swzb(sr, sc * 2 + 1)) = rv1;
    if (qt >= 1){
      rk0 = *(const short8*)(gk - 64 * D_);      rk1 = *(const short8*)(gk - 64 * D_ + 8);
      rv0 = *(const short8*)(gv - 64);           rv1 = *(const short8*)(gv - 64 + 8);
    }
  }
  __syncthreads();

  for (int t = qt; t >= 0; --t){
    int kv0 = t << 6;
    char* curK = (char*)lK[t & 1];
    char* curV = (char*)lV[t & 1];

    // stage tile t-1 into the other buffer; issue loads for tile t-2
    if (t >= 1){
      char* dK = (char*)lK[(t - 1) & 1];
      char* dV = (char*)lV[(t - 1) & 1];
      *(short8*)(dK + swzb(sr, sc * 2))     = rk0;
      *(short8*)(dK + swzb(sr, sc * 2 + 1)) = rk1;
      *(short8*)(dV + swzb(sr, sc * 2))     = rv0;
      *(short8*)(dV + swzb(sr, sc * 2 + 1)) = rv1;
      if (t >= 2){
        const u16* gk = kp + (size_t)((t - 2) * 64 + sr) * D_ + sc * 16;
        const u16* gv = vp + (size_t)sr * T_ + (t - 2) * 64 + sc * 16;
        rk0 = *(const short8*)gk;   rk1 = *(const short8*)(gk + 8);
        rv0 = *(const short8*)gv;   rv1 = *(const short8*)(gv + 8);
      }
    }

    // ---- S^T = K * Q^T ----
    f32x4 accs[4] = {};
    __builtin_amdgcn_s_setprio(1);
    #pragma unroll
    for (int ks = 0; ks < 2; ks++){
      short8 kf[4];
      #pragma unroll
      for (int n = 0; n < 4; n++)
        kf[n] = *(const short8*)(curK + swzb(n * 16 + c, ks * 4 + g));
      #pragma unroll
      for (int n = 0; n < 4; n++)
        accs[n] = __builtin_amdgcn_mfma_f32_16x16x32_bf16(kf[n], qf[ks], accs[n], 0, 0, 0);
    }
    __builtin_amdgcn_s_setprio(0);

    // ---- softmax (bias = slope2*kv only; row term cancels) ----
    float base = slope2 * (float)kv0;
    float s[16];
    #pragma unroll
    for (int n = 0; n < 4; n++)
      #pragma unroll
      for (int r = 0; r < 4; r++)
        s[n * 4 + r] = fmaf(accs[n][r], scl2, base + boff[n * 4 + r]);
    if (t == qt){                        // only the diagonal tile masks
      int qm = qb + c - kv0;
      #pragma unroll
      for (int n = 0; n < 4; n++)
        #pragma unroll
        for (int r = 0; r < 4; r++)
          s[n * 4 + r] = (n * 16 + g * 4 + r > qm) ? -1e30f : s[n * 4 + r];
    }
    // balanced max tree (depth 4)
    float t0 = fmaxf(s[0], s[1]),   t1 = fmaxf(s[2], s[3]);
    float t2 = fmaxf(s[4], s[5]),   t3 = fmaxf(s[6], s[7]);
    float t4 = fmaxf(s[8], s[9]),   t5 = fmaxf(s[10], s[11]);
    float t6 = fmaxf(s[12], s[13]), t7 = fmaxf(s[14], s[15]);
    float u0 = fmaxf(t0, t1), u1 = fmaxf(t2, t3);
    float u2 = fmaxf(t4, t5), u3 = fmaxf(t6, t7);
    float pm = fmaxf(fmaxf(u0, u1), fmaxf(u2, u3));
    pm = fmaxf(pm, __shfl_xor(pm, 16));
    pm = fmaxf(pm, __shfl_xor(pm, 32));
    if (!__all(pm <= mrun + 8.0f)){      // defer-max: rescale only on real growth
      float nm = fmaxf(mrun, pm);
      float al = exp2f(mrun - nm);
      lrun *= al;
      #pragma unroll
      for (int n = 0; n < 4; n++)
        #pragma unroll
        for (int r = 0; r < 4; r++)
          acco[n][r] *= al;
      mrun = nm;
    }
    float p[16], ps = 0.f;
    #pragma unroll
    for (int i = 0; i < 16; i++){ p[i] = exp2f(s[i] - mrun); ps += p[i]; }
    lrun += ps;                          // per-lane partial; merged at the end
    #pragma unroll
    for (int n = 0; n < 4; n++){
      u32 w0 = ((u32)f2bf(p[n * 4 + 1]) << 16) | f2bf(p[n * 4 + 0]);
      u32 w1 = ((u32)f2bf(p[n * 4 + 3]) << 16) | f2bf(p[n * 4 + 2]);
      uint2 wp; wp.x = w0; wp.y = w1;
      *(uint2*)(lPw + swzb(c, 2 * n + (g >> 1)) + ((g & 1) << 3)) = wp;
    }

    // ---- O^T += V^T * P^T ----
    __builtin_amdgcn_s_setprio(1);
    #pragma unroll
    for (int ks = 0; ks < 2; ks++){
      short8 vf[4], pf;
      pf = *(const short8*)(lPw + swzb(c, ks * 4 + g));
      #pragma unroll
      for (int n = 0; n < 4; n++)
        vf[n] = *(const short8*)(curV + swzb(n * 16 + c, ks * 4 + g));
      #pragma unroll
      for (int n = 0; n < 4; n++)
        acco[n] = __builtin_amdgcn_mfma_f32_16x16x32_bf16(vf[n], pf, acco[n], 0, 0, 0);
    }
    __builtin_amdgcn_s_setprio(0);

    __syncthreads();                     // tile t done; buf^1 staged for t-1
  }

  // epilogue: merge per-lane partial sums across the 4 groups, normalize, store
  {
    float ls = lrun;
    ls += __shfl_xor(ls, 16);
    ls += __shfl_xor(ls, 32);
    float inv = 1.0f / ls;
    size_t rowoff = (size_t)(b * T_ + qb + c) * C_ + h * D_;
    #pragma unroll
    for (int n = 0; n < 4; n++){
      u32 w0 = ((u32)f2bf(acco[n][1] * inv) << 16) | f2bf(acco[n][0] * inv);
      u32 w1 = ((u32)f2bf(acco[n][3] * inv) << 16) | f2bf(acco[n][2] * inv);
      uint2 wp; wp.x = w0; wp.y = w1;
      *(uint2*)&y[rowoff + n * 16 + g * 4] = wp;
    }
  }
}

// ---------------- launcher ----------------
// Workspace layout (40 MB peak, aliased by lifetime):
//   [0,  8)  xb  -> vtw   [8,14) wab   [14,16) wpt
//   [16,24) qw   [24,32) kw   [32,40) vw -> yb
extern "C" void kernel_launch(void* const* d_in, const int* in_sizes, int n_in,
                              void* d_out, int out_size, void* d_ws, size_t ws_size,
                              hipStream_t stream){
  const float* x      = (const float*)d_in[0];
  const float* W_attn = (const float*)d_in[1];
  const float* b_attn = (const float*)d_in[2];
  const float* W_proj = (const float*)d_in[3];
  const float* b_proj = (const float*)d_in[4];
  const float* temp   = (const float*)d_in[5];
  float* out = (float*)d_out;

  if (ws_size < (size_t)41943040) return;  // need 40 MB scratch
  char* ws = (char*)d_ws;
  u16* xb  = (u16*)(ws);
  u16* wab = (u16*)(ws + 8388608);
  u16* wpt = (u16*)(ws + 14680064);
  u16* qw  = (u16*)(ws + 16777216);
  u16* kw  = (u16*)(ws + 25165824);
  u16* vw  = (u16*)(ws + 33554432);
  u16* vtw = (u16*)(ws);                    // overlays xb
  u16* yb  = (u16*)(ws + 33554432);         // overlays vw

  k_cvt_x<<<2048, 256, 0, stream>>>(x, xb);
  k_transW<<<dim3(96, 32), dim3(32, 8), 0, stream>>>(W_attn, wab, 1024, 3072);
  k_transW<<<dim3(32, 32), dim3(32, 8), 0, stream>>>(W_proj, wpt, 1024, 1024);
  k_gemm<0><<<dim3(24, 32), 256, 0, stream>>>(xb, wab, b_attn, nullptr, qw, kw, vw,
                                              4096, 3072, 1024);
  k_transV<<<dim3(64, 2, 32), dim3(32, 8), 0, stream>>>(vw, vtw);
  k_attn<<<dim3(32, 32), 256, 0, stream>>>(qw, kw, vtw, yb, temp);
  k_gemm<1><<<dim3(8, 32), 256, 0, stream>>>(yb, wpt, b_proj, out, nullptr, nullptr, nullptr,
                                             4096, 1024, 1024);
}

// Round 7
// 197.409 us; speedup vs baseline: 1.5167x; 1.0181x over previous
//
#include <hip/hip_runtime.h>
#include <hip/hip_bf16.h>
#include <math.h>

#define B_ 2
#define T_ 2048
#define C_ 1024
#define H_ 16
#define D_ 64
#define M_ (B_*T_)

typedef unsigned short u16;
typedef unsigned int u32;
typedef __attribute__((ext_vector_type(8))) short short8;
typedef __attribute__((ext_vector_type(4))) float f32x4;

__device__ inline u16 f2bf(float f){
  union { float f; unsigned u; } v; v.f = f;
  unsigned r = (v.u + 0x7FFF + ((v.u >> 16) & 1)) >> 16;
  return (u16)r;
}

// pair convert via v_cvt_pk_bf16_f32 (RNE, packed u32: lo in low 16)
__device__ inline u32 pkbf(float lo, float hi){
  __hip_bfloat162 h = __float22bfloat162_rn(make_float2(lo, hi));
  union { __hip_bfloat162 h; u32 u; } v; v.h = h;
  return v.u;
}

__device__ inline void gload_lds16(const void* g, void* l){
  __builtin_amdgcn_global_load_lds(
      (const __attribute__((address_space(1))) unsigned*)g,
      (__attribute__((address_space(3))) unsigned*)l, 16, 0, 0);
}

// byte offset into a [rows][64]u16 (128B-row) LDS tile with 16B-chunk XOR swizzle
__device__ inline int swzb(int row, int chunk){
  return (row << 7) | ((chunk ^ (row & 7)) << 4);
}

// ---------------- x -> bf16 ----------------
__global__ void k_cvt_x(const float* __restrict__ x, u16* __restrict__ xb){
  int i = (blockIdx.x * 256 + threadIdx.x) * 8;
  float4 a = *(const float4*)(x + i);
  float4 b = *(const float4*)(x + i + 4);
  short8 o;
  o[0] = (short)f2bf(a.x); o[1] = (short)f2bf(a.y);
  o[2] = (short)f2bf(a.z); o[3] = (short)f2bf(a.w);
  o[4] = (short)f2bf(b.x); o[5] = (short)f2bf(b.y);
  o[6] = (short)f2bf(b.z); o[7] = (short)f2bf(b.w);
  *(short8*)(xb + i) = o;
}

// ---------------- W [K][N] fp32 -> Wt [N][K] bf16 ----------------
__global__ void k_transW(const float* __restrict__ W, u16* __restrict__ Wt, int K, int N){
  __shared__ float t[32][33];
  int bn = blockIdx.x * 32, bk = blockIdx.y * 32;
  int tx = threadIdx.x, ty = threadIdx.y; // (32,8)
  #pragma unroll
  for (int i = 0; i < 32; i += 8)
    t[ty + i][tx] = W[(size_t)(bk + ty + i) * N + bn + tx];
  __syncthreads();
  #pragma unroll
  for (int i = 0; i < 32; i += 8)
    Wt[(size_t)(bn + ty + i) * K + bk + tx] = f2bf(t[tx][ty + i]);
}

// ---------------- v [bh][T][D] -> vt [bh][D][T] (bf16) ----------------
__global__ void k_transV(const u16* __restrict__ v, u16* __restrict__ vt){
  __shared__ u16 t[32][33];
  int bh = blockIdx.z;
  int t0 = blockIdx.x * 32, d0 = blockIdx.y * 32;
  int tx = threadIdx.x, ty = threadIdx.y;
  const u16* vs = v + (size_t)bh * T_ * D_;
  u16* vd = vt + (size_t)bh * T_ * D_;
  #pragma unroll
  for (int i = 0; i < 32; i += 8)
    t[ty + i][tx] = vs[(size_t)(t0 + ty + i) * D_ + d0 + tx];
  __syncthreads();
  #pragma unroll
  for (int i = 0; i < 32; i += 8)
    vd[(size_t)(d0 + ty + i) * T_ + t0 + tx] = t[tx][ty + i];
}

// ---------------- 128x128 GEMM, A[M][K] * Bt[N][K]^T, bf16 MFMA ----------------
// XCD-chunked block swizzle (T1): requires gridDim.x*gridDim.y % 8 == 0.
template<int EPI>
__launch_bounds__(256, 2)
__global__ void k_gemm(const u16* __restrict__ A, const u16* __restrict__ Bt,
                       const float* __restrict__ bias, float* __restrict__ outF,
                       u16* __restrict__ oq, u16* __restrict__ ok, u16* __restrict__ ov,
                       int M, int N, int K){
  __shared__ u16 lA[128 * 32];
  __shared__ u16 lB[128 * 32];
  int tid = threadIdx.x, lane = tid & 63, wv = tid >> 6;
  unsigned nwg = gridDim.x * gridDim.y;
  unsigned bid = blockIdx.y * gridDim.x + blockIdx.x;
  unsigned nbid = (bid & 7) * (nwg >> 3) + (bid >> 3);
  int bm = (int)(nbid / gridDim.x) * 128, bn = (int)(nbid % gridDim.x) * 128;
  int wr = (wv >> 1) * 64, wc = (wv & 1) * 64;
  f32x4 acc[4][4] = {};

  const u16* Ab = A + (size_t)(bm + wv * 32 + (lane >> 2)) * K + (lane & 3) * 8;
  const u16* Bb = Bt + (size_t)(bn + wv * 32 + (lane >> 2)) * K + (lane & 3) * 8;
  u16* lAd = &lA[wv * 1024];
  u16* lBd = &lB[wv * 1024];
  int ar = wr + (lane & 15);
  int br = wc + (lane & 15);
  int kc = (lane >> 4) * 8;

  for (int k0 = 0; k0 < K; k0 += 32){
    gload_lds16(Ab + k0, lAd);
    gload_lds16(Ab + k0 + (size_t)16 * K, lAd + 512);
    gload_lds16(Bb + k0, lBd);
    gload_lds16(Bb + k0 + (size_t)16 * K, lBd + 512);
    __syncthreads();
    short8 afr[4], bfr[4];
    #pragma unroll
    for (int m = 0; m < 4; m++) afr[m] = *(const short8*)&lA[(ar + m * 16) * 32 + kc];
    #pragma unroll
    for (int n = 0; n < 4; n++) bfr[n] = *(const short8*)&lB[(br + n * 16) * 32 + kc];
    #pragma unroll
    for (int m = 0; m < 4; m++)
      #pragma unroll
      for (int n = 0; n < 4; n++)
        acc[m][n] = __builtin_amdgcn_mfma_f32_16x16x32_bf16(afr[m], bfr[n], acc[m][n], 0, 0, 0);
    __syncthreads();
  }

  if (EPI == 1){
    #pragma unroll
    for (int m = 0; m < 4; m++){
      int gmB = bm + wr + m * 16 + ((lane >> 4) << 2);
      #pragma unroll
      for (int n = 0; n < 4; n++){
        int gn = bn + wc + n * 16 + (lane & 15);
        float bia = bias[gn];
        #pragma unroll
        for (int j = 0; j < 4; j++)
          outF[(size_t)(gmB + j) * N + gn] = acc[m][n][j] + bia;
      }
    }
  } else {
    #pragma unroll
    for (int m = 0; m < 4; m++){
      int gmB = bm + wr + m * 16 + ((lane >> 4) << 2);
      #pragma unroll
      for (int n = 0; n < 4; n++){
        int gn = bn + wc + n * 16 + (lane & 15);
        float bia = bias[gn];
        int part = gn >> 10;
        int col = gn & 1023;
        int h = col >> 6, d = col & 63;
        u16* dst = (part == 0) ? oq : (part == 1) ? ok : ov;
        #pragma unroll
        for (int j = 0; j < 4; j++){
          int gm = gmB + j;
          int b = gm >> 11, t = gm & 2047;
          dst[((size_t)(b * H_ + h) * T_ + t) * D_ + d] = f2bf(acc[m][n][j] + bia);
        }
      }
    }
  }
}

// ---------------- flash attention: 4 waves x 16 q-rows, LDS dbuf K/V ----------------
// q,k: [bh][T][D] bf16; vt: [bh][D][T] bf16; y: [b][t][C] bf16 (head-major cols)
// S^T = mfma(K,Q): lane holds q=lane&15(=c), kv = n*16 + 4*(lane>>4) + r
// O^T = mfma(V^T,P^T): lane holds q=c, d = n*16 + 4*(lane>>4) + r
// ALiBi row-constant term dropped (softmax shift-invariance); descending kv
// (diagonal first) so defer-max skips later rescales; K/V LDS double-buffer
// with one barrier per tile and 2-tile global prefetch distance.
// P->bf16 via v_cvt_pk_bf16_f32 pair casts (was the VALU hotspot).
// 4 blocks/CU: 4 x 40KB LDS = 160KB exactly; VGPR ~64 << 128 cap.
__launch_bounds__(256, 4)
__global__ void k_attn(const u16* __restrict__ q, const u16* __restrict__ k,
                       const u16* __restrict__ vt, u16* __restrict__ y,
                       const float* __restrict__ tempPtr){
  __shared__ u16 lK[2][64 * 64];       // [kv][d], XOR-swizzled
  __shared__ u16 lV[2][64 * 64];       // [d][kv], XOR-swizzled
  __shared__ u16 lP[4][16 * 64];       // per-wave [q][kv], XOR-swizzled
  const float LOG2E = 1.44269504089f;
  int tid = threadIdx.x, lane = tid & 63, wv = tid >> 6;
  int g = lane >> 4, c = lane & 15;
  int bh = blockIdx.x, h = bh & (H_ - 1), b = bh >> 4;
  int qt = 31 - blockIdx.y;            // longest q-tiles dispatched first
  int q0 = qt * 64;
  int qb = q0 + wv * 16;
  float scl2 = LOG2E / (8.0f * tempPtr[0]);
  float slope2 = exp2f(-0.5f * (float)(h + 1)) * LOG2E;
  const u16* qp = q + (size_t)bh * T_ * D_;
  const u16* kp = k + (size_t)bh * T_ * D_;
  const u16* vp = vt + (size_t)bh * T_ * D_;
  char* lPw = (char*)lP[wv];

  // Q fragments (B-operand of S^T): lane holds Q[qb+c][ks*32+g*8 ..+7]
  short8 qf[2];
  #pragma unroll
  for (int ks = 0; ks < 2; ks++)
    qf[ks] = *(const short8*)&qp[(size_t)(qb + c) * D_ + ks * 32 + g * 8];

  // per-lane ALiBi: bias = slope2*kv = slope2*kv0 + boff[i]
  float boff[16];
  #pragma unroll
  for (int n = 0; n < 4; n++)
    #pragma unroll
    for (int r = 0; r < 4; r++)
      boff[n * 4 + r] = slope2 * (float)(n * 16 + g * 4 + r);

  float mrun = -1e30f, lrun = 0.f;
  f32x4 acco[4] = {};

  // staging: thread covers row sr, 16B-chunks sc*2 / sc*2+1 of K and V tiles
  int sr = tid >> 2, sc = tid & 3;
  short8 rk0, rk1, rv0, rv1;

  // prologue: load+write tile qt, load tile qt-1
  {
    const u16* gk = kp + (size_t)(q0 + sr) * D_ + sc * 16;
    const u16* gv = vp + (size_t)sr * T_ + q0 + sc * 16;
    rk0 = *(const short8*)gk;       rk1 = *(const short8*)(gk + 8);
    rv0 = *(const short8*)gv;       rv1 = *(const short8*)(gv + 8);
    char* dK = (char*)lK[qt & 1];
    char* dV = (char*)lV[qt & 1];
    *(short8*)(dK + swzb(sr, sc * 2))     = rk0;
    *(short8*)(dK + swzb(sr, sc * 2 + 1)) = rk1;
    *(short8*)(dV + swzb(sr, sc * 2))     = rv0;
    *(short8*)(dV + swzb(sr, sc * 2 + 1)) = rv1;
    if (qt >= 1){
      rk0 = *(const short8*)(gk - 64 * D_);      rk1 = *(const short8*)(gk - 64 * D_ + 8);
      rv0 = *(const short8*)(gv - 64);           rv1 = *(const short8*)(gv - 64 + 8);
    }
  }
  __syncthreads();

  for (int t = qt; t >= 0; --t){
    int kv0 = t << 6;
    char* curK = (char*)lK[t & 1];
    char* curV = (char*)lV[t & 1];

    // stage tile t-1 into the other buffer; issue loads for tile t-2
    if (t >= 1){
      char* dK = (char*)lK[(t - 1) & 1];
      char* dV = (char*)lV[(t - 1) & 1];
      *(short8*)(dK + swzb(sr, sc * 2))     = rk0;
      *(short8*)(dK + swzb(sr, sc * 2 + 1)) = rk1;
      *(short8*)(dV + swzb(sr, sc * 2))     = rv0;
      *(short8*)(dV + swzb(sr, sc * 2 + 1)) = rv1;
      if (t >= 2){
        const u16* gk = kp + (size_t)((t - 2) * 64 + sr) * D_ + sc * 16;
        const u16* gv = vp + (size_t)sr * T_ + (t - 2) * 64 + sc * 16;
        rk0 = *(const short8*)gk;   rk1 = *(const short8*)(gk + 8);
        rv0 = *(const short8*)gv;   rv1 = *(const short8*)(gv + 8);
      }
    }

    // ---- S^T = K * Q^T ----
    f32x4 accs[4] = {};
    __builtin_amdgcn_s_setprio(1);
    #pragma unroll
    for (int ks = 0; ks < 2; ks++){
      short8 kf[4];
      #pragma unroll
      for (int n = 0; n < 4; n++)
        kf[n] = *(const short8*)(curK + swzb(n * 16 + c, ks * 4 + g));
      #pragma unroll
      for (int n = 0; n < 4; n++)
        accs[n] = __builtin_amdgcn_mfma_f32_16x16x32_bf16(kf[n], qf[ks], accs[n], 0, 0, 0);
    }
    __builtin_amdgcn_s_setprio(0);

    // ---- softmax (bias = slope2*kv only; row term cancels) ----
    float base = slope2 * (float)kv0;
    float s[16];
    #pragma unroll
    for (int n = 0; n < 4; n++)
      #pragma unroll
      for (int r = 0; r < 4; r++)
        s[n * 4 + r] = fmaf(accs[n][r], scl2, base + boff[n * 4 + r]);
    if (t == qt){                        // only the diagonal tile masks
      int qm = qb + c - kv0;
      #pragma unroll
      for (int n = 0; n < 4; n++)
        #pragma unroll
        for (int r = 0; r < 4; r++)
          s[n * 4 + r] = (n * 16 + g * 4 + r > qm) ? -1e30f : s[n * 4 + r];
    }
    // balanced max tree (depth 4)
    float t0 = fmaxf(s[0], s[1]),   t1 = fmaxf(s[2], s[3]);
    float t2 = fmaxf(s[4], s[5]),   t3 = fmaxf(s[6], s[7]);
    float t4 = fmaxf(s[8], s[9]),   t5 = fmaxf(s[10], s[11]);
    float t6 = fmaxf(s[12], s[13]), t7 = fmaxf(s[14], s[15]);
    float u0 = fmaxf(t0, t1), u1 = fmaxf(t2, t3);
    float u2 = fmaxf(t4, t5), u3 = fmaxf(t6, t7);
    float pm = fmaxf(fmaxf(u0, u1), fmaxf(u2, u3));
    pm = fmaxf(pm, __shfl_xor(pm, 16));
    pm = fmaxf(pm, __shfl_xor(pm, 32));
    if (!__all(pm <= mrun + 8.0f)){      // defer-max: rescale only on real growth
      float nm = fmaxf(mrun, pm);
      float al = exp2f(mrun - nm);
      lrun *= al;
      #pragma unroll
      for (int n = 0; n < 4; n++)
        #pragma unroll
        for (int r = 0; r < 4; r++)
          acco[n][r] *= al;
      mrun = nm;
    }
    float p[16], ps = 0.f;
    #pragma unroll
    for (int i = 0; i < 16; i++){ p[i] = exp2f(s[i] - mrun); ps += p[i]; }
    lrun += ps;                          // per-lane partial; merged at the end
    #pragma unroll
    for (int n = 0; n < 4; n++){
      uint2 wp;
      wp.x = pkbf(p[n * 4 + 0], p[n * 4 + 1]);
      wp.y = pkbf(p[n * 4 + 2], p[n * 4 + 3]);
      *(uint2*)(lPw + swzb(c, 2 * n + (g >> 1)) + ((g & 1) << 3)) = wp;
    }

    // ---- O^T += V^T * P^T ----
    __builtin_amdgcn_s_setprio(1);
    #pragma unroll
    for (int ks = 0; ks < 2; ks++){
      short8 vf[4], pf;
      pf = *(const short8*)(lPw + swzb(c, ks * 4 + g));
      #pragma unroll
      for (int n = 0; n < 4; n++)
        vf[n] = *(const short8*)(curV + swzb(n * 16 + c, ks * 4 + g));
      #pragma unroll
      for (int n = 0; n < 4; n++)
        acco[n] = __builtin_amdgcn_mfma_f32_16x16x32_bf16(vf[n], pf, acco[n], 0, 0, 0);
    }
    __builtin_amdgcn_s_setprio(0);

    __syncthreads();                     // tile t done; buf^1 staged for t-1
  }

  // epilogue: merge per-lane partial sums across the 4 groups, normalize, store
  {
    float ls = lrun;
    ls += __shfl_xor(ls, 16);
    ls += __shfl_xor(ls, 32);
    float inv = 1.0f / ls;
    size_t rowoff = (size_t)(b * T_ + qb + c) * C_ + h * D_;
    #pragma unroll
    for (int n = 0; n < 4; n++){
      uint2 wp;
      wp.x = pkbf(acco[n][0] * inv, acco[n][1] * inv);
      wp.y = pkbf(acco[n][2] * inv, acco[n][3] * inv);
      *(uint2*)&y[rowoff + n * 16 + g * 4] = wp;
    }
  }
}

// ---------------- launcher ----------------
// Workspace layout (40 MB peak, aliased by lifetime):
//   [0,  8)  xb  -> vtw   [8,14) wab   [14,16) wpt
//   [16,24) qw   [24,32) kw   [32,40) vw -> yb
extern "C" void kernel_launch(void* const* d_in, const int* in_sizes, int n_in,
                              void* d_out, int out_size, void* d_ws, size_t ws_size,
                              hipStream_t stream){
  const float* x      = (const float*)d_in[0];
  const float* W_attn = (const float*)d_in[1];
  const float* b_attn = (const float*)d_in[2];
  const float* W_proj = (const float*)d_in[3];
  const float* b_proj = (const float*)d_in[4];
  const float* temp   = (const float*)d_in[5];
  float* out = (float*)d_out;

  if (ws_size < (size_t)41943040) return;  // need 40 MB scratch
  char* ws = (char*)d_ws;
  u16* xb  = (u16*)(ws);
  u16* wab = (u16*)(ws + 8388608);
  u16* wpt = (u16*)(ws + 14680064);
  u16* qw  = (u16*)(ws + 16777216);
  u16* kw  = (u16*)(ws + 25165824);
  u16* vw  = (u16*)(ws + 33554432);
  u16* vtw = (u16*)(ws);                    // overlays xb
  u16* yb  = (u16*)(ws + 33554432);         // overlays vw

  k_cvt_x<<<2048, 256, 0, stream>>>(x, xb);
  k_transW<<<dim3(96, 32), dim3(32, 8), 0, stream>>>(W_attn, wab, 1024, 3072);
  k_transW<<<dim3(32, 32), dim3(32, 8), 0, stream>>>(W_proj, wpt, 1024, 1024);
  k_gemm<0><<<dim3(24, 32), 256, 0, stream>>>(xb, wab, b_attn, nullptr, qw, kw, vw,
                                              4096, 3072, 1024);
  k_transV<<<dim3(64, 2, 32), dim3(32, 8), 0, stream>>>(vw, vtw);
  k_attn<<<dim3(32, 32), 256, 0, stream>>>(qw, kw, vtw, yb, temp);
  k_gemm<1><<<dim3(8, 32), 256, 0, stream>>>(yb, wpt, b_proj, out, nullptr, nullptr, nullptr,
                                             4096, 1024, 1024);
}

// Round 9
// 195.267 us; speedup vs baseline: 1.5334x; 1.0110x over previous
//
#include <hip/hip_runtime.h>
#include <hip/hip_bf16.h>
#include <math.h>

#define B_ 2
#define T_ 2048
#define C_ 1024
#define H_ 16
#define D_ 64
#define M_ (B_*T_)

typedef unsigned short u16;
typedef unsigned int u32;
typedef __attribute__((ext_vector_type(8))) short short8;
typedef __attribute__((ext_vector_type(4))) float f32x4;

__device__ inline u16 f2bf(float f){
  union { float f; unsigned u; } v; v.f = f;
  unsigned r = (v.u + 0x7FFF + ((v.u >> 16) & 1)) >> 16;
  return (u16)r;
}

// pair convert via v_cvt_pk_bf16_f32 (RNE, packed u32: lo in low 16)
__device__ inline u32 pkbf(float lo, float hi){
  __hip_bfloat162 h = __float22bfloat162_rn(make_float2(lo, hi));
  union { __hip_bfloat162 h; u32 u; } v; v.h = h;
  return v.u;
}

__device__ inline void gload_lds16(const void* g, void* l){
  __builtin_amdgcn_global_load_lds(
      (const __attribute__((address_space(1))) unsigned*)g,
      (__attribute__((address_space(3))) unsigned*)l, 16, 0, 0);
}

// byte offset into a [rows][64]u16 (128B-row) LDS tile with 16B-chunk XOR swizzle
__device__ inline int swzb(int row, int chunk){
  return (row << 7) | ((chunk ^ (row & 7)) << 4);
}

// ---------------- x -> bf16 ----------------
__global__ void k_cvt_x(const float* __restrict__ x, u16* __restrict__ xb){
  int i = (blockIdx.x * 256 + threadIdx.x) * 8;
  float4 a = *(const float4*)(x + i);
  float4 b = *(const float4*)(x + i + 4);
  short8 o;
  o[0] = (short)f2bf(a.x); o[1] = (short)f2bf(a.y);
  o[2] = (short)f2bf(a.z); o[3] = (short)f2bf(a.w);
  o[4] = (short)f2bf(b.x); o[5] = (short)f2bf(b.y);
  o[6] = (short)f2bf(b.z); o[7] = (short)f2bf(b.w);
  *(short8*)(xb + i) = o;
}

// ---------------- W [K][N] fp32 -> Wt [N][K] bf16 ----------------
__global__ void k_transW(const float* __restrict__ W, u16* __restrict__ Wt, int K, int N){
  __shared__ float t[32][33];
  int bn = blockIdx.x * 32, bk = blockIdx.y * 32;
  int tx = threadIdx.x, ty = threadIdx.y; // (32,8)
  #pragma unroll
  for (int i = 0; i < 32; i += 8)
    t[ty + i][tx] = W[(size_t)(bk + ty + i) * N + bn + tx];
  __syncthreads();
  #pragma unroll
  for (int i = 0; i < 32; i += 8)
    Wt[(size_t)(bn + ty + i) * K + bk + tx] = f2bf(t[tx][ty + i]);
}

// ---------------- v [bh][T][D] -> vt [bh][D][T] (bf16) ----------------
__global__ void k_transV(const u16* __restrict__ v, u16* __restrict__ vt){
  __shared__ u16 t[32][33];
  int bh = blockIdx.z;
  int t0 = blockIdx.x * 32, d0 = blockIdx.y * 32;
  int tx = threadIdx.x, ty = threadIdx.y;
  const u16* vs = v + (size_t)bh * T_ * D_;
  u16* vd = vt + (size_t)bh * T_ * D_;
  #pragma unroll
  for (int i = 0; i < 32; i += 8)
    t[ty + i][tx] = vs[(size_t)(t0 + ty + i) * D_ + d0 + tx];
  __syncthreads();
  #pragma unroll
  for (int i = 0; i < 32; i += 8)
    vd[(size_t)(d0 + ty + i) * T_ + t0 + tx] = t[tx][ty + i];
}

// ---------------- 128x128 GEMM, A[M][K] * Bt[N][K]^T, bf16 MFMA ----------------
// XCD-chunked block swizzle (T1): requires gridDim.x*gridDim.y % 8 == 0.
template<int EPI>
__launch_bounds__(256, 2)
__global__ void k_gemm(const u16* __restrict__ A, const u16* __restrict__ Bt,
                       const float* __restrict__ bias, float* __restrict__ outF,
                       u16* __restrict__ oq, u16* __restrict__ ok, u16* __restrict__ ov,
                       int M, int N, int K){
  __shared__ u16 lA[128 * 32];
  __shared__ u16 lB[128 * 32];
  int tid = threadIdx.x, lane = tid & 63, wv = tid >> 6;
  unsigned nwg = gridDim.x * gridDim.y;
  unsigned bid = blockIdx.y * gridDim.x + blockIdx.x;
  unsigned nbid = (bid & 7) * (nwg >> 3) + (bid >> 3);
  int bm = (int)(nbid / gridDim.x) * 128, bn = (int)(nbid % gridDim.x) * 128;
  int wr = (wv >> 1) * 64, wc = (wv & 1) * 64;
  f32x4 acc[4][4] = {};

  const u16* Ab = A + (size_t)(bm + wv * 32 + (lane >> 2)) * K + (lane & 3) * 8;
  const u16* Bb = Bt + (size_t)(bn + wv * 32 + (lane >> 2)) * K + (lane & 3) * 8;
  u16* lAd = &lA[wv * 1024];
  u16* lBd = &lB[wv * 1024];
  int ar = wr + (lane & 15);
  int br = wc + (lane & 15);
  int kc = (lane >> 4) * 8;

  for (int k0 = 0; k0 < K; k0 += 32){
    gload_lds16(Ab + k0, lAd);
    gload_lds16(Ab + k0 + (size_t)16 * K, lAd + 512);
    gload_lds16(Bb + k0, lBd);
    gload_lds16(Bb + k0 + (size_t)16 * K, lBd + 512);
    __syncthreads();
    short8 afr[4], bfr[4];
    #pragma unroll
    for (int m = 0; m < 4; m++) afr[m] = *(const short8*)&lA[(ar + m * 16) * 32 + kc];
    #pragma unroll
    for (int n = 0; n < 4; n++) bfr[n] = *(const short8*)&lB[(br + n * 16) * 32 + kc];
    #pragma unroll
    for (int m = 0; m < 4; m++)
      #pragma unroll
      for (int n = 0; n < 4; n++)
        acc[m][n] = __builtin_amdgcn_mfma_f32_16x16x32_bf16(afr[m], bfr[n], acc[m][n], 0, 0, 0);
    __syncthreads();
  }

  if (EPI == 1){
    #pragma unroll
    for (int m = 0; m < 4; m++){
      int gmB = bm + wr + m * 16 + ((lane >> 4) << 2);
      #pragma unroll
      for (int n = 0; n < 4; n++){
        int gn = bn + wc + n * 16 + (lane & 15);
        float bia = bias[gn];
        #pragma unroll
        for (int j = 0; j < 4; j++)
          outF[(size_t)(gmB + j) * N + gn] = acc[m][n][j] + bia;
      }
    }
  } else {
    #pragma unroll
    for (int m = 0; m < 4; m++){
      int gmB = bm + wr + m * 16 + ((lane >> 4) << 2);
      #pragma unroll
      for (int n = 0; n < 4; n++){
        int gn = bn + wc + n * 16 + (lane & 15);
        float bia = bias[gn];
        int part = gn >> 10;
        int col = gn & 1023;
        int h = col >> 6, d = col & 63;
        u16* dst = (part == 0) ? oq : (part == 1) ? ok : ov;
        #pragma unroll
        for (int j = 0; j < 4; j++){
          int gm = gmB + j;
          int b = gm >> 11, t = gm & 2047;
          dst[((size_t)(b * H_ + h) * T_ + t) * D_ + d] = f2bf(acc[m][n][j] + bia);
        }
      }
    }
  }
}

// ---------------- flash attention: 4 waves x 16 q-rows, 32KB LDS ----------------
// q,k: [bh][T][D] bf16; vt: [bh][D][T] bf16; y: [b][t][C] bf16 (head-major cols)
// S^T = mfma(K,Q): lane holds q=lane&15(=c), kv = n*16 + 4*(lane>>4) + r
// O^T = mfma(V^T,P^T): lane holds q=c, d = n*16 + 4*(lane>>4) + r
// K SINGLE-buffered (consumed only at tile start), V double-buffered, P per-
// wave: 8+16+8 = 32KB -> 4 blocks/CU even under a 128KB effective LDS limit.
// Schedule per tile t (descending kv, diagonal first):
//   QK(t) | barrier1 | write K(t-1) | softmax+P | PV(t) | write V(t-1),
//   issue loads(t-2) | barrier2
// V(t-1) write after barrier1 is safe: the prior reader of that V buffer
// (PV(t+1)) completed before every wave passed barrier1.
__launch_bounds__(256, 4)
__global__ void k_attn(const u16* __restrict__ q, const u16* __restrict__ k,
                       const u16* __restrict__ vt, u16* __restrict__ y,
                       const float* __restrict__ tempPtr){
  __shared__ u16 lK[64 * 64];          // single buffer [kv][d], XOR-swizzled
  __shared__ u16 lV[2][64 * 64];       // dbuf [d][kv], XOR-swizzled
  __shared__ u16 lP[4][16 * 64];       // per-wave [q][kv], XOR-swizzled
  const float LOG2E = 1.44269504089f;
  int tid = threadIdx.x, lane = tid & 63, wv = tid >> 6;
  int g = lane >> 4, c = lane & 15;
  int bh = blockIdx.x, h = bh & (H_ - 1), b = bh >> 4;
  int qt = 31 - blockIdx.y;            // longest q-tiles dispatched first
  int q0 = qt * 64;
  int qb = q0 + wv * 16;
  float scl2 = LOG2E / (8.0f * tempPtr[0]);
  float slope2 = exp2f(-0.5f * (float)(h + 1)) * LOG2E;
  const u16* qp = q + (size_t)bh * T_ * D_;
  const u16* kp = k + (size_t)bh * T_ * D_;
  const u16* vp = vt + (size_t)bh * T_ * D_;
  char* lKc = (char*)lK;
  char* lPw = (char*)lP[wv];

  // Q fragments (B-operand of S^T): lane holds Q[qb+c][ks*32+g*8 ..+7]
  short8 qf[2];
  #pragma unroll
  for (int ks = 0; ks < 2; ks++)
    qf[ks] = *(const short8*)&qp[(size_t)(qb + c) * D_ + ks * 32 + g * 8];

  // per-lane ALiBi: bias = slope2*kv = slope2*kv0 + boff[i]
  float boff[16];
  #pragma unroll
  for (int n = 0; n < 4; n++)
    #pragma unroll
    for (int r = 0; r < 4; r++)
      boff[n * 4 + r] = slope2 * (float)(n * 16 + g * 4 + r);

  float mrun = -1e30f, lrun = 0.f;
  f32x4 acco[4] = {};

  // staging: thread covers row sr, 16B-chunks sc*2 / sc*2+1 of K and V tiles
  int sr = tid >> 2, sc = tid & 3;
  short8 rk0, rk1, rv0, rv1;

  // prologue: load+write tile qt (K and V), load regs for tile qt-1
  {
    const u16* gk = kp + (size_t)(q0 + sr) * D_ + sc * 16;
    const u16* gv = vp + (size_t)sr * T_ + q0 + sc * 16;
    rk0 = *(const short8*)gk;       rk1 = *(const short8*)(gk + 8);
    rv0 = *(const short8*)gv;       rv1 = *(const short8*)(gv + 8);
    *(short8*)(lKc + swzb(sr, sc * 2))     = rk0;
    *(short8*)(lKc + swzb(sr, sc * 2 + 1)) = rk1;
    char* dV = (char*)lV[qt & 1];
    *(short8*)(dV + swzb(sr, sc * 2))     = rv0;
    *(short8*)(dV + swzb(sr, sc * 2 + 1)) = rv1;
    if (qt >= 1){
      rk0 = *(const short8*)(gk - 64 * D_);      rk1 = *(const short8*)(gk - 64 * D_ + 8);
      rv0 = *(const short8*)(gv - 64);           rv1 = *(const short8*)(gv - 64 + 8);
    }
  }
  __syncthreads();

  for (int t = qt; t >= 0; --t){
    int kv0 = t << 6;
    char* curV = (char*)lV[t & 1];

    // ---- S^T = K * Q^T (from the single K buffer) ----
    f32x4 accs[4] = {};
    __builtin_amdgcn_s_setprio(1);
    #pragma unroll
    for (int ks = 0; ks < 2; ks++){
      short8 kf[4];
      #pragma unroll
      for (int n = 0; n < 4; n++)
        kf[n] = *(const short8*)(lKc + swzb(n * 16 + c, ks * 4 + g));
      #pragma unroll
      for (int n = 0; n < 4; n++)
        accs[n] = __builtin_amdgcn_mfma_f32_16x16x32_bf16(kf[n], qf[ks], accs[n], 0, 0, 0);
    }
    __builtin_amdgcn_s_setprio(0);

    __syncthreads();                     // barrier1: all QK reads of lK done

    // stage K(t-1) into the (now free) single K buffer
    if (t >= 1){
      *(short8*)(lKc + swzb(sr, sc * 2))     = rk0;
      *(short8*)(lKc + swzb(sr, sc * 2 + 1)) = rk1;
    }

    // ---- softmax (bias = slope2*kv only; row term cancels) ----
    float base = slope2 * (float)kv0;
    float s[16];
    #pragma unroll
    for (int n = 0; n < 4; n++)
      #pragma unroll
      for (int r = 0; r < 4; r++)
        s[n * 4 + r] = fmaf(accs[n][r], scl2, base + boff[n * 4 + r]);
    if (t == qt){                        // only the diagonal tile masks
      int qm = qb + c - kv0;
      #pragma unroll
      for (int n = 0; n < 4; n++)
        #pragma unroll
        for (int r = 0; r < 4; r++)
          s[n * 4 + r] = (n * 16 + g * 4 + r > qm) ? -1e30f : s[n * 4 + r];
    }
    // max reduce via v_max3-friendly nested triples (8 ops)
    float a0 = fmaxf(fmaxf(s[0], s[1]), s[2]);
    float a1 = fmaxf(fmaxf(s[3], s[4]), s[5]);
    float a2 = fmaxf(fmaxf(s[6], s[7]), s[8]);
    float a3 = fmaxf(fmaxf(s[9], s[10]), s[11]);
    float a4 = fmaxf(fmaxf(s[12], s[13]), s[14]);
    float pm = fmaxf(fmaxf(fmaxf(a0, a1), a2), fmaxf(fmaxf(a3, a4), s[15]));
    pm = fmaxf(pm, __shfl_xor(pm, 16));
    pm = fmaxf(pm, __shfl_xor(pm, 32));
    if (!__all(pm <= mrun + 8.0f)){      // defer-max: rescale only on real growth
      float nm = fmaxf(mrun, pm);
      float al = exp2f(mrun - nm);
      lrun *= al;
      #pragma unroll
      for (int n = 0; n < 4; n++)
        #pragma unroll
        for (int r = 0; r < 4; r++)
          acco[n][r] *= al;
      mrun = nm;
    }
    float p[16], ps = 0.f;
    #pragma unroll
    for (int i = 0; i < 16; i++){ p[i] = exp2f(s[i] - mrun); ps += p[i]; }
    lrun += ps;                          // per-lane partial; merged at the end
    #pragma unroll
    for (int n = 0; n < 4; n++){
      uint2 wp;
      wp.x = pkbf(p[n * 4 + 0], p[n * 4 + 1]);
      wp.y = pkbf(p[n * 4 + 2], p[n * 4 + 3]);
      *(uint2*)(lPw + swzb(c, 2 * n + (g >> 1)) + ((g & 1) << 3)) = wp;
    }

    // ---- O^T += V^T * P^T ----
    __builtin_amdgcn_s_setprio(1);
    #pragma unroll
    for (int ks = 0; ks < 2; ks++){
      short8 vf[4], pf;
      pf = *(const short8*)(lPw + swzb(c, ks * 4 + g));
      #pragma unroll
      for (int n = 0; n < 4; n++)
        vf[n] = *(const short8*)(curV + swzb(n * 16 + c, ks * 4 + g));
      #pragma unroll
      for (int n = 0; n < 4; n++)
        acco[n] = __builtin_amdgcn_mfma_f32_16x16x32_bf16(vf[n], pf, acco[n], 0, 0, 0);
    }
    __builtin_amdgcn_s_setprio(0);

    // stage V(t-1) into the other V buffer; issue loads for tile t-2
    if (t >= 1){
      char* dV = (char*)lV[(t - 1) & 1];
      *(short8*)(dV + swzb(sr, sc * 2))     = rv0;
      *(short8*)(dV + swzb(sr, sc * 2 + 1)) = rv1;
      if (t >= 2){
        const u16* gk = kp + (size_t)((t - 2) * 64 + sr) * D_ + sc * 16;
        const u16* gv = vp + (size_t)sr * T_ + (t - 2) * 64 + sc * 16;
        rk0 = *(const short8*)gk;   rk1 = *(const short8*)(gk + 8);
        rv0 = *(const short8*)gv;   rv1 = *(const short8*)(gv + 8);
      }
    }

    __syncthreads();                     // barrier2: K(t-1)/V(t-1) staged
  }

  // epilogue: merge per-lane partial sums across the 4 groups, normalize, store
  {
    float ls = lrun;
    ls += __shfl_xor(ls, 16);
    ls += __shfl_xor(ls, 32);
    float inv = 1.0f / ls;
    size_t rowoff = (size_t)(b * T_ + qb + c) * C_ + h * D_;
    #pragma unroll
    for (int n = 0; n < 4; n++){
      uint2 wp;
      wp.x = pkbf(acco[n][0] * inv, acco[n][1] * inv);
      wp.y = pkbf(acco[n][2] * inv, acco[n][3] * inv);
      *(uint2*)&y[rowoff + n * 16 + g * 4] = wp;
    }
  }
}

// ---------------- launcher ----------------
// Workspace layout (40 MB peak, aliased by lifetime):
//   [0,  8)  xb  -> vtw   [8,14) wab   [14,16) wpt
//   [16,24) qw   [24,32) kw   [32,40) vw -> yb
extern "C" void kernel_launch(void* const* d_in, const int* in_sizes, int n_in,
                              void* d_out, int out_size, void* d_ws, size_t ws_size,
                              hipStream_t stream){
  const float* x      = (const float*)d_in[0];
  const float* W_attn = (const float*)d_in[1];
  const float* b_attn = (const float*)d_in[2];
  const float* W_proj = (const float*)d_in[3];
  const float* b_proj = (const float*)d_in[4];
  const float* temp   = (const float*)d_in[5];
  float* out = (float*)d_out;

  if (ws_size < (size_t)41943040) return;  // need 40 MB scratch
  char* ws = (char*)d_ws;
  u16* xb  = (u16*)(ws);
  u16* wab = (u16*)(ws + 8388608);
  u16* wpt = (u16*)(ws + 14680064);
  u16* qw  = (u16*)(ws + 16777216);
  u16* kw  = (u16*)(ws + 25165824);
  u16* vw  = (u16*)(ws + 33554432);
  u16* vtw = (u16*)(ws);                    // overlays xb
  u16* yb  = (u16*)(ws + 33554432);         // overlays vw

  k_cvt_x<<<2048, 256, 0, stream>>>(x, xb);
  k_transW<<<dim3(96, 32), dim3(32, 8), 0, stream>>>(W_attn, wab, 1024, 3072);
  k_transW<<<dim3(32, 32), dim3(32, 8), 0, stream>>>(W_proj, wpt, 1024, 1024);
  k_gemm<0><<<dim3(24, 32), 256, 0, stream>>>(xb, wab, b_attn, nullptr, qw, kw, vw,
                                              4096, 3072, 1024);
  k_transV<<<dim3(64, 2, 32), dim3(32, 8), 0, stream>>>(vw, vtw);
  k_attn<<<dim3(32, 32), 256, 0, stream>>>(qw, kw, vtw, yb, temp);
  k_gemm<1><<<dim3(8, 32), 256, 0, stream>>>(yb, wpt, b_proj, out, nullptr, nullptr, nullptr,
                                             4096, 1024, 1024);
}

// Round 10
// 188.158 us; speedup vs baseline: 1.5913x; 1.0378x over previous
//
#include <hip/hip_runtime.h>
#include <hip/hip_bf16.h>
#include <math.h>

#define B_ 2
#define T_ 2048
#define C_ 1024
#define H_ 16
#define D_ 64
#define M_ (B_*T_)

typedef unsigned short u16;
typedef unsigned int u32;
typedef __attribute__((ext_vector_type(8))) short short8;
typedef __attribute__((ext_vector_type(4))) float f32x4;

__device__ inline u16 f2bf(float f){
  union { float f; unsigned u; } v; v.f = f;
  unsigned r = (v.u + 0x7FFF + ((v.u >> 16) & 1)) >> 16;
  return (u16)r;
}

// pair convert via v_cvt_pk_bf16_f32 (RNE, packed u32: lo in low 16)
__device__ inline u32 pkbf(float lo, float hi){
  __hip_bfloat162 h = __float22bfloat162_rn(make_float2(lo, hi));
  union { __hip_bfloat162 h; u32 u; } v; v.h = h;
  return v.u;
}

__device__ inline void gload_lds16(const void* g, void* l){
  __builtin_amdgcn_global_load_lds(
      (const __attribute__((address_space(1))) unsigned*)g,
      (__attribute__((address_space(3))) unsigned*)l, 16, 0, 0);
}

// byte offset into a [rows][64]u16 (128B-row) LDS tile with 16B-chunk XOR swizzle
__device__ inline int swzb(int row, int chunk){
  return (row << 7) | ((chunk ^ (row & 7)) << 4);
}

// ---------------- fused prep: x->bf16  |  W_attn^T  |  W_proj^T ----------------
// grid 6144: [0,2048) cvt_x, [2048,5120) transW(W_attn), [5120,6144) transW(W_proj)
__global__ void k_prep(const float* __restrict__ x, u16* __restrict__ xb,
                       const float* __restrict__ Wa, u16* __restrict__ wab,
                       const float* __restrict__ Wp, u16* __restrict__ wpt){
  __shared__ float tbuf[32][33];
  int bx = blockIdx.x, tid = threadIdx.x;
  if (bx < 2048){
    int i = (bx * 256 + tid) * 8;
    float4 a = *(const float4*)(x + i);
    float4 b = *(const float4*)(x + i + 4);
    short8 o;
    o[0] = (short)f2bf(a.x); o[1] = (short)f2bf(a.y);
    o[2] = (short)f2bf(a.z); o[3] = (short)f2bf(a.w);
    o[4] = (short)f2bf(b.x); o[5] = (short)f2bf(b.y);
    o[6] = (short)f2bf(b.z); o[7] = (short)f2bf(b.w);
    *(short8*)(xb + i) = o;
    return;
  }
  const float* W; u16* Wt; int N, bn, bk;
  if (bx < 5120){
    int idx = bx - 2048;                 // W_attn: K=1024, N=3072 (96 x 32 tiles)
    W = Wa; Wt = wab; N = 3072;
    bn = (idx % 96) * 32; bk = (idx / 96) * 32;
  } else {
    int idx = bx - 5120;                 // W_proj: K=1024, N=1024 (32 x 32 tiles)
    W = Wp; Wt = wpt; N = 1024;
    bn = (idx % 32) * 32; bk = (idx / 32) * 32;
  }
  int tx = tid & 31, ty = tid >> 5;      // (32,8)
  #pragma unroll
  for (int i = 0; i < 32; i += 8)
    tbuf[ty + i][tx] = W[(size_t)(bk + ty + i) * N + bn + tx];
  __syncthreads();
  #pragma unroll
  for (int i = 0; i < 32; i += 8)
    Wt[(size_t)(bn + ty + i) * 1024 + bk + tx] = f2bf(tbuf[tx][ty + i]);
}

// ---------------- 128x128 GEMM, A[M][K] * Bt[N][K]^T, bf16 MFMA ----------------
// XCD-chunked block swizzle (T1): requires gridDim.x*gridDim.y % 8 == 0.
// EPI 0: scatter q/k per-head [bh][t][d]; V written TRANSPOSED [bh][d][t]
//        (4 consecutive t per lane -> one 8B store) -- replaces k_transV.
// EPI 1: fp32 out + bias.
template<int EPI>
__launch_bounds__(256, 2)
__global__ void k_gemm(const u16* __restrict__ A, const u16* __restrict__ Bt,
                       const float* __restrict__ bias, float* __restrict__ outF,
                       u16* __restrict__ oq, u16* __restrict__ ok, u16* __restrict__ ovt,
                       int M, int N, int K){
  __shared__ u16 lA[128 * 32];
  __shared__ u16 lB[128 * 32];
  int tid = threadIdx.x, lane = tid & 63, wv = tid >> 6;
  unsigned nwg = gridDim.x * gridDim.y;
  unsigned bid = blockIdx.y * gridDim.x + blockIdx.x;
  unsigned nbid = (bid & 7) * (nwg >> 3) + (bid >> 3);
  int bm = (int)(nbid / gridDim.x) * 128, bn = (int)(nbid % gridDim.x) * 128;
  int wr = (wv >> 1) * 64, wc = (wv & 1) * 64;
  f32x4 acc[4][4] = {};

  const u16* Ab = A + (size_t)(bm + wv * 32 + (lane >> 2)) * K + (lane & 3) * 8;
  const u16* Bb = Bt + (size_t)(bn + wv * 32 + (lane >> 2)) * K + (lane & 3) * 8;
  u16* lAd = &lA[wv * 1024];
  u16* lBd = &lB[wv * 1024];
  int ar = wr + (lane & 15);
  int br = wc + (lane & 15);
  int kc = (lane >> 4) * 8;

  for (int k0 = 0; k0 < K; k0 += 32){
    gload_lds16(Ab + k0, lAd);
    gload_lds16(Ab + k0 + (size_t)16 * K, lAd + 512);
    gload_lds16(Bb + k0, lBd);
    gload_lds16(Bb + k0 + (size_t)16 * K, lBd + 512);
    __syncthreads();
    short8 afr[4], bfr[4];
    #pragma unroll
    for (int m = 0; m < 4; m++) afr[m] = *(const short8*)&lA[(ar + m * 16) * 32 + kc];
    #pragma unroll
    for (int n = 0; n < 4; n++) bfr[n] = *(const short8*)&lB[(br + n * 16) * 32 + kc];
    #pragma unroll
    for (int m = 0; m < 4; m++)
      #pragma unroll
      for (int n = 0; n < 4; n++)
        acc[m][n] = __builtin_amdgcn_mfma_f32_16x16x32_bf16(afr[m], bfr[n], acc[m][n], 0, 0, 0);
    __syncthreads();
  }

  if (EPI == 1){
    #pragma unroll
    for (int m = 0; m < 4; m++){
      int gmB = bm + wr + m * 16 + ((lane >> 4) << 2);
      #pragma unroll
      for (int n = 0; n < 4; n++){
        int gn = bn + wc + n * 16 + (lane & 15);
        float bia = bias[gn];
        #pragma unroll
        for (int j = 0; j < 4; j++)
          outF[(size_t)(gmB + j) * N + gn] = acc[m][n][j] + bia;
      }
    }
  } else {
    #pragma unroll
    for (int m = 0; m < 4; m++){
      int gmB = bm + wr + m * 16 + ((lane >> 4) << 2);
      int b = gmB >> 11, t = gmB & 2047;      // j=0..3 stays in-batch (gmB%4==0)
      #pragma unroll
      for (int n = 0; n < 4; n++){
        int gn = bn + wc + n * 16 + (lane & 15);
        float bia = bias[gn];
        int part = gn >> 10;
        int col = gn & 1023;
        int h = col >> 6, d = col & 63;
        if (part == 2){
          // V^T: [bh][d][t], 4 consecutive t -> one 8B store
          uint2 wp;
          wp.x = pkbf(acc[m][n][0] + bia, acc[m][n][1] + bia);
          wp.y = pkbf(acc[m][n][2] + bia, acc[m][n][3] + bia);
          *(uint2*)&ovt[((size_t)(b * H_ + h) * D_ + d) * T_ + t] = wp;
        } else {
          u16* dst = part ? ok : oq;
          #pragma unroll
          for (int j = 0; j < 4; j++)
            dst[((size_t)(b * H_ + h) * T_ + t + j) * D_ + d] = f2bf(acc[m][n][j] + bia);
        }
      }
    }
  }
}

// ---------------- flash attention: 4 waves x 16 q-rows, LDS dbuf K/V ----------------
// (round-7 kernel verbatim: measured 50.6us, the best attn config so far)
// q,k: [bh][T][D] bf16; vt: [bh][D][T] bf16; y: [b][t][C] bf16 (head-major cols)
// S^T = mfma(K,Q): lane holds q=lane&15(=c), kv = n*16 + 4*(lane>>4) + r
// O^T = mfma(V^T,P^T): lane holds q=c, d = n*16 + 4*(lane>>4) + r
__launch_bounds__(256, 4)
__global__ void k_attn(const u16* __restrict__ q, const u16* __restrict__ k,
                       const u16* __restrict__ vt, u16* __restrict__ y,
                       const float* __restrict__ tempPtr){
  __shared__ u16 lK[2][64 * 64];       // [kv][d], XOR-swizzled
  __shared__ u16 lV[2][64 * 64];       // [d][kv], XOR-swizzled
  __shared__ u16 lP[4][16 * 64];       // per-wave [q][kv], XOR-swizzled
  const float LOG2E = 1.44269504089f;
  int tid = threadIdx.x, lane = tid & 63, wv = tid >> 6;
  int g = lane >> 4, c = lane & 15;
  int bh = blockIdx.x, h = bh & (H_ - 1), b = bh >> 4;
  int qt = 31 - blockIdx.y;            // longest q-tiles dispatched first
  int q0 = qt * 64;
  int qb = q0 + wv * 16;
  float scl2 = LOG2E / (8.0f * tempPtr[0]);
  float slope2 = exp2f(-0.5f * (float)(h + 1)) * LOG2E;
  const u16* qp = q + (size_t)bh * T_ * D_;
  const u16* kp = k + (size_t)bh * T_ * D_;
  const u16* vp = vt + (size_t)bh * T_ * D_;
  char* lPw = (char*)lP[wv];

  short8 qf[2];
  #pragma unroll
  for (int ks = 0; ks < 2; ks++)
    qf[ks] = *(const short8*)&qp[(size_t)(qb + c) * D_ + ks * 32 + g * 8];

  float boff[16];
  #pragma unroll
  for (int n = 0; n < 4; n++)
    #pragma unroll
    for (int r = 0; r < 4; r++)
      boff[n * 4 + r] = slope2 * (float)(n * 16 + g * 4 + r);

  float mrun = -1e30f, lrun = 0.f;
  f32x4 acco[4] = {};

  int sr = tid >> 2, sc = tid & 3;
  short8 rk0, rk1, rv0, rv1;

  {
    const u16* gk = kp + (size_t)(q0 + sr) * D_ + sc * 16;
    const u16* gv = vp + (size_t)sr * T_ + q0 + sc * 16;
    rk0 = *(const short8*)gk;       rk1 = *(const short8*)(gk + 8);
    rv0 = *(const short8*)gv;       rv1 = *(const short8*)(gv + 8);
    char* dK = (char*)lK[qt & 1];
    char* dV = (char*)lV[qt & 1];
    *(short8*)(dK + swzb(sr, sc * 2))     = rk0;
    *(short8*)(dK + swzb(sr, sc * 2 + 1)) = rk1;
    *(short8*)(dV + swzb(sr, sc * 2))     = rv0;
    *(short8*)(dV + swzb(sr, sc * 2 + 1)) = rv1;
    if (qt >= 1){
      rk0 = *(const short8*)(gk - 64 * D_);      rk1 = *(const short8*)(gk - 64 * D_ + 8);
      rv0 = *(const short8*)(gv - 64);           rv1 = *(const short8*)(gv - 64 + 8);
    }
  }
  __syncthreads();

  for (int t = qt; t >= 0; --t){
    int kv0 = t << 6;
    char* curK = (char*)lK[t & 1];
    char* curV = (char*)lV[t & 1];

    if (t >= 1){
      char* dK = (char*)lK[(t - 1) & 1];
      char* dV = (char*)lV[(t - 1) & 1];
      *(short8*)(dK + swzb(sr, sc * 2))     = rk0;
      *(short8*)(dK + swzb(sr, sc * 2 + 1)) = rk1;
      *(short8*)(dV + swzb(sr, sc * 2))     = rv0;
      *(short8*)(dV + swzb(sr, sc * 2 + 1)) = rv1;
      if (t >= 2){
        const u16* gk = kp + (size_t)((t - 2) * 64 + sr) * D_ + sc * 16;
        const u16* gv = vp + (size_t)sr * T_ + (t - 2) * 64 + sc * 16;
        rk0 = *(const short8*)gk;   rk1 = *(const short8*)(gk + 8);
        rv0 = *(const short8*)gv;   rv1 = *(const short8*)(gv + 8);
      }
    }

    // ---- S^T = K * Q^T ----
    f32x4 accs[4] = {};
    __builtin_amdgcn_s_setprio(1);
    #pragma unroll
    for (int ks = 0; ks < 2; ks++){
      short8 kf[4];
      #pragma unroll
      for (int n = 0; n < 4; n++)
        kf[n] = *(const short8*)(curK + swzb(n * 16 + c, ks * 4 + g));
      #pragma unroll
      for (int n = 0; n < 4; n++)
        accs[n] = __builtin_amdgcn_mfma_f32_16x16x32_bf16(kf[n], qf[ks], accs[n], 0, 0, 0);
    }
    __builtin_amdgcn_s_setprio(0);

    // ---- softmax (bias = slope2*kv only; row term cancels) ----
    float base = slope2 * (float)kv0;
    float s[16];
    #pragma unroll
    for (int n = 0; n < 4; n++)
      #pragma unroll
      for (int r = 0; r < 4; r++)
        s[n * 4 + r] = fmaf(accs[n][r], scl2, base + boff[n * 4 + r]);
    if (t == qt){
      int qm = qb + c - kv0;
      #pragma unroll
      for (int n = 0; n < 4; n++)
        #pragma unroll
        for (int r = 0; r < 4; r++)
          s[n * 4 + r] = (n * 16 + g * 4 + r > qm) ? -1e30f : s[n * 4 + r];
    }
    float t0 = fmaxf(s[0], s[1]),   t1 = fmaxf(s[2], s[3]);
    float t2 = fmaxf(s[4], s[5]),   t3 = fmaxf(s[6], s[7]);
    float t4 = fmaxf(s[8], s[9]),   t5 = fmaxf(s[10], s[11]);
    float t6 = fmaxf(s[12], s[13]), t7 = fmaxf(s[14], s[15]);
    float u0 = fmaxf(t0, t1), u1 = fmaxf(t2, t3);
    float u2 = fmaxf(t4, t5), u3 = fmaxf(t6, t7);
    float pm = fmaxf(fmaxf(u0, u1), fmaxf(u2, u3));
    pm = fmaxf(pm, __shfl_xor(pm, 16));
    pm = fmaxf(pm, __shfl_xor(pm, 32));
    if (!__all(pm <= mrun + 8.0f)){      // defer-max
      float nm = fmaxf(mrun, pm);
      float al = exp2f(mrun - nm);
      lrun *= al;
      #pragma unroll
      for (int n = 0; n < 4; n++)
        #pragma unroll
        for (int r = 0; r < 4; r++)
          acco[n][r] *= al;
      mrun = nm;
    }
    float p[16], ps = 0.f;
    #pragma unroll
    for (int i = 0; i < 16; i++){ p[i] = exp2f(s[i] - mrun); ps += p[i]; }
    lrun += ps;
    #pragma unroll
    for (int n = 0; n < 4; n++){
      uint2 wp;
      wp.x = pkbf(p[n * 4 + 0], p[n * 4 + 1]);
      wp.y = pkbf(p[n * 4 + 2], p[n * 4 + 3]);
      *(uint2*)(lPw + swzb(c, 2 * n + (g >> 1)) + ((g & 1) << 3)) = wp;
    }

    // ---- O^T += V^T * P^T ----
    __builtin_amdgcn_s_setprio(1);
    #pragma unroll
    for (int ks = 0; ks < 2; ks++){
      short8 vf[4], pf;
      pf = *(const short8*)(lPw + swzb(c, ks * 4 + g));
      #pragma unroll
      for (int n = 0; n < 4; n++)
        vf[n] = *(const short8*)(curV + swzb(n * 16 + c, ks * 4 + g));
      #pragma unroll
      for (int n = 0; n < 4; n++)
        acco[n] = __builtin_amdgcn_mfma_f32_16x16x32_bf16(vf[n], pf, acco[n], 0, 0, 0);
    }
    __builtin_amdgcn_s_setprio(0);

    __syncthreads();
  }

  {
    float ls = lrun;
    ls += __shfl_xor(ls, 16);
    ls += __shfl_xor(ls, 32);
    float inv = 1.0f / ls;
    size_t rowoff = (size_t)(b * T_ + qb + c) * C_ + h * D_;
    #pragma unroll
    for (int n = 0; n < 4; n++){
      uint2 wp;
      wp.x = pkbf(acco[n][0] * inv, acco[n][1] * inv);
      wp.y = pkbf(acco[n][2] * inv, acco[n][3] * inv);
      *(uint2*)&y[rowoff + n * 16 + g * 4] = wp;
    }
  }
}

// ---------------- launcher (4 kernels) ----------------
// Workspace layout (40 MB peak, aliased by lifetime):
//   [0,  8)  xb  (gemm0 input)  -> yb (attn out; xb dead after gemm0)
//   [8, 14)  wab (dead after gemm0)
//   [14,16)  wpt (live until gemm1)
//   [16,24)  qw   [24,32) kw   [32,40) vtw  (gemm0 writes V^T directly)
extern "C" void kernel_launch(void* const* d_in, const int* in_sizes, int n_in,
                              void* d_out, int out_size, void* d_ws, size_t ws_size,
                              hipStream_t stream){
  const float* x      = (const float*)d_in[0];
  const float* W_attn = (const float*)d_in[1];
  const float* b_attn = (const float*)d_in[2];
  const float* W_proj = (const float*)d_in[3];
  const float* b_proj = (const float*)d_in[4];
  const float* temp   = (const float*)d_in[5];
  float* out = (float*)d_out;

  if (ws_size < (size_t)41943040) return;  // need 40 MB scratch
  char* ws = (char*)d_ws;
  u16* xb  = (u16*)(ws);
  u16* wab = (u16*)(ws + 8388608);
  u16* wpt = (u16*)(ws + 14680064);
  u16* qw  = (u16*)(ws + 16777216);
  u16* kw  = (u16*)(ws + 25165824);
  u16* vtw = (u16*)(ws + 33554432);
  u16* yb  = (u16*)(ws);                    // overlays xb (dead after gemm0)

  k_prep<<<6144, 256, 0, stream>>>(x, xb, W_attn, wab, W_proj, wpt);
  k_gemm<0><<<dim3(24, 32), 256, 0, stream>>>(xb, wab, b_attn, nullptr, qw, kw, vtw,
                                              4096, 3072, 1024);
  k_attn<<<dim3(32, 32), 256, 0, stream>>>(qw, kw, vtw, yb, temp);
  k_gemm<1><<<dim3(8, 32), 256, 0, stream>>>(yb, wpt, b_proj, out, nullptr, nullptr, nullptr,
                                             4096, 1024, 1024);
}